// Round 10
// baseline (2466.632 us; speedup 1.0000x reference)
//
#include <hip/hip_runtime.h>

#define H 64
#define T_STEPS 2048
#define SEQS 4           // sequences per block; B col c carries seq c&3
#define CHUNK_H 144      // halves per K-chunk: 256B data + 32B pad (bank spread)
#define SLOT_H (6 * CHUNK_H)

typedef _Float16 f16x8 __attribute__((ext_vector_type(8)));
typedef float    f32x4 __attribute__((ext_vector_type(4)));

// ---- native transcendentals (R20-proven): v_exp_f32 / v_rcp_f32 ----
__device__ __forceinline__ float fexp2(float x) {
#if __has_builtin(__builtin_amdgcn_exp2f)
    return __builtin_amdgcn_exp2f(x);
#else
    float r; asm("v_exp_f32 %0, %1" : "=v"(r) : "v"(x)); return r;
#endif
}
__device__ __forceinline__ float frcp(float x) {
#if __has_builtin(__builtin_amdgcn_rcpf)
    return __builtin_amdgcn_rcpf(x);
#else
    float r; asm("v_rcp_f32 %0, %1" : "=v"(r) : "v"(x)); return r;
#endif
}
// pre-acts arrive PRE-SCALED by -log2e (i,f,o rows) / -2log2e (g rows)
__device__ __forceinline__ float sig_y(float y)  { return frcp(1.0f + fexp2(y)); }
__device__ __forceinline__ float tanh_y(float y) { return 2.0f * frcp(1.0f + fexp2(y)) - 1.0f; }
#define NL2E  (-1.44269504088896341f)
#define N2L2E (-2.88539008177792681f)

// load 8 consecutive f32, scale, -> f16x8 (setup only)
__device__ __forceinline__ f16x8 ldcvt8s(const float* __restrict__ p, float s) {
    float4 a = ((const float4*)p)[0];
    float4 c = ((const float4*)p)[1];
    f16x8 r;
    r[0]=(_Float16)(s*a.x); r[1]=(_Float16)(s*a.y);
    r[2]=(_Float16)(s*a.z); r[3]=(_Float16)(s*a.w);
    r[4]=(_Float16)(s*c.x); r[5]=(_Float16)(s*c.y);
    r[6]=(_Float16)(s*c.z); r[7]=(_Float16)(s*c.w);
    return r;
}

#define MFMA(a, b, c) __builtin_amdgcn_mfma_f32_16x16x32_f16((a), (b), (c), 0, 0, 0)

// R23 (= R22 resubmitted; R22's bench was lost to a container failure).
// REPLICATED B-COLUMNS — NO SHUFFLE BETWEEN MFMA AND ACT.
// R21 ledger (closes exactly): per SIMD VALU-port = MFMA 776 + trans 640
// + regular ~430 = 1846 ≈ measured; step 2690 => ~850 stall, with
// __shfl_xor (ds_swizzle: LDS-pipe hop ON the serial chain) and 2.1e7
// bank conflicts as the prime suspects.
// Fix: B col c carries seq c&3 (cols 4-way redundant; the MFMA computes
// 16 cols regardless). Lane (kg,lj) of wave w then holds in its OWN
// D-frag all 4 gates of (cell 4w+kg, seq lj&3) for all 3 layers; it
// picks layer u=lj>>2 (u==3 idle) locally. Zero cross-lane ops.
// LDS: S[slot][chunk 6][seq 4][32 halves], chunk stride 288B ->
// B-reads <=2-way banks (free, m136), 4-way same-addr broadcast free.
// Everything else R16/R20/R21-proven: AGPR-parked A, bias(+x) in C,
// L0 t=p / L1 t=p-1 / L2 t=p-2, read slot (p+1)&1, write p&1, 1 barrier.
__global__ __launch_bounds__(1024, 4)
void lstm3_r23(const float* __restrict__ x,
               const float* __restrict__ Wih0, const float* __restrict__ Whh0,
               const float* __restrict__ bih0, const float* __restrict__ bhh0,
               const float* __restrict__ Wih1, const float* __restrict__ Whh1,
               const float* __restrict__ bih1, const float* __restrict__ bhh1,
               const float* __restrict__ Wih2, const float* __restrict__ Whh2,
               const float* __restrict__ bih2, const float* __restrict__ bhh2,
               const float* __restrict__ Wout, const float* __restrict__ bout,
               float* __restrict__ out)
{
    __shared__ __align__(16) _Float16 S[2 * SLOT_H];   // 3456 B
    __shared__ __align__(16) float h2f[SEQS][H];       // 1 KB

    const int tid  = threadIdx.x;
    const int w    = tid >> 6;           // wave 0..15 = M-tile
    const int l    = tid & 63;
    const int lj   = l & 15;             // A row-in-tile / B,D column
    const int kg   = l >> 4;             // k-group / D row-quad
    const int cell = 4 * w + kg;         // cell of this lane's D rows
    const int u    = lj >> 2;            // act role: layer (3 = idle)
    const int sq   = lj & 3;             // act role: seq = this lane's COLUMN's seq
    const int seqx = blockIdx.x * SEQS + sq;

    // ---- A-fragments (R16-proven mapping), pre-scaled by gate row ----
    const int cellA = 4 * w + (lj >> 2);
    const int gateA = lj & 3;
    const int wrow  = gateA * H + cellA;
    const int kc    = kg * 8;
    const float sA  = (gateA == 2) ? N2L2E : NL2E;

    f16x8 A00 = ldcvt8s(Whh0 + wrow * H + kc,      sA);   // L0 <- h0 lo
    f16x8 A01 = ldcvt8s(Whh0 + wrow * H + 32 + kc, sA);   // L0 <- h0 hi
    f16x8 A10 = ldcvt8s(Wih1 + wrow * H + kc,      sA);   // L1 <- h0 lo
    f16x8 A11 = ldcvt8s(Wih1 + wrow * H + 32 + kc, sA);   // L1 <- h0 hi
    f16x8 A12 = ldcvt8s(Whh1 + wrow * H + kc,      sA);   // L1 <- h1 lo
    f16x8 A13 = ldcvt8s(Whh1 + wrow * H + 32 + kc, sA);   // L1 <- h1 hi
    f16x8 A20 = ldcvt8s(Wih2 + wrow * H + kc,      sA);   // L2 <- h1 lo
    f16x8 A21 = ldcvt8s(Wih2 + wrow * H + 32 + kc, sA);   // L2 <- h1 hi
    f16x8 A22 = ldcvt8s(Whh2 + wrow * H + kc,      sA);   // L2 <- h2 lo
    f16x8 A23 = ldcvt8s(Whh2 + wrow * H + 32 + kc, sA);   // L2 <- h2 hi
    asm volatile("" : "+a"(A00), "+a"(A01), "+a"(A10), "+a"(A11));
    asm volatile("" : "+a"(A12), "+a"(A13), "+a"(A20), "+a"(A21));
    asm volatile("" : "+a"(A22), "+a"(A23));

    // ---- C-operand bias frags (rows = gates of `cell`, col-invariant) ----
    f32x4 cb0, cb1, cb2;
    float wx[8];
#pragma unroll
    for (int r = 0; r < 4; ++r) {
        const float sr = (r == 2) ? N2L2E : NL2E;
        cb0[r] = sr * (bih0[r * H + cell] + bhh0[r * H + cell]);
        cb1[r] = sr * (bih1[r * H + cell] + bhh1[r * H + cell]);
        cb2[r] = sr * (bih2[r * H + cell] + bhh2[r * H + cell]);
        wx[2 * r]     = sr * Wih0[(r * H + cell) * 2];
        wx[2 * r + 1] = sr * Wih0[(r * H + cell) * 2 + 1];
    }
    float cst = 0.f;                     // state of this lane's act role
    const float* xseq = x + (size_t)seqx * T_STEPS * 2;

    // ---- zero S (both slots incl. pads) ----
    if (tid < (int)(sizeof(S) / 4)) ((float*)S)[tid] = 0.f;
    __syncthreads();

    // this lane's write target (loop-invariant except slot):
    const int kpos = u * 64 + cell;                   // K index of produced h
    _Float16* const wr0 = S + (kpos >> 5) * CHUNK_H + sq * 32 + (kpos & 31);

    const f32x4 z = {0.f, 0.f, 0.f, 0.f};

#pragma unroll 1
    for (int p = 0; p <= T_STEPS + 1; ++p) {
        const bool on0 = (p < T_STEPS);
        const bool on1 = (p >= 1) && (p <= T_STEPS);
        const bool on2 = (p >= 2);

        // x_t of this lane's COLUMN seq (16-way replicated load; L1 bcast)
        const int px = on0 ? p : (T_STEPS - 1);
        float2 xt = *(const float2*)(xseq + 2 * px);

        // B-frags: lane (kg, sq) reads chunk c at sq*64 + kg*16 bytes.
        // 4-way same-addr broadcast (free) + <=2-way bank alias (free).
        const _Float16* rb = S + ((p + 1) & 1) * SLOT_H + sq * 32 + kg * 8;
        f16x8 b0 = *(const f16x8*)(rb + 0 * CHUNK_H);   // h0 lo
        f16x8 b1 = *(const f16x8*)(rb + 1 * CHUNK_H);   // h0 hi
        f16x8 b2 = *(const f16x8*)(rb + 2 * CHUNK_H);   // h1 lo
        f16x8 b3 = *(const f16x8*)(rb + 3 * CHUNK_H);   // h1 hi
        f16x8 b4 = *(const f16x8*)(rb + 4 * CHUNK_H);   // h2 lo
        f16x8 b5 = *(const f16x8*)(rb + 5 * CHUNK_H);   // h2 hi

        // L0 C-operand: scaled bias + per-COLUMN x-term
        f32x4 c0;
#pragma unroll
        for (int r = 0; r < 4; ++r)
            c0[r] = cb0[r] + wx[2 * r] * xt.x + wx[2 * r + 1] * xt.y;

        // ---- 10 MFMAs (biases ride C; split accumulators) ----
        f32x4 g0 = z, g1 = z, g2 = z;
        if (on0) { g0 = MFMA(A00, b0, c0);  g0 = MFMA(A01, b1, g0); }
        if (on1) {
            f32x4 ga = MFMA(A10, b0, cb1); ga = MFMA(A11, b1, ga);
            f32x4 gb = MFMA(A12, b2, z);   gb = MFMA(A13, b3, gb);
            g1 = ga + gb;
        }
        if (on2) {
            f32x4 gc = MFMA(A20, b2, cb2); gc = MFMA(A21, b3, gc);
            f32x4 gd = MFMA(A22, b4, z);   gd = MFMA(A23, b5, gd);
            g2 = gc + gd;
        }

        // ---- act straight from this lane's OWN D-frag (no shuffles) ----
        f32x4 pre = (u == 0) ? g0 : (u == 1) ? g1 : g2;
        const bool act_on = (u == 0) ? on0 : (u == 1) ? on1
                          : (u == 2) ? on2 : false;
        float i_ = sig_y(pre[0]), f_ = sig_y(pre[1]);
        float gg = tanh_y(pre[2]), o_ = sig_y(pre[3]);
        float cn = f_ * cst + i_ * gg;
        float hh = o_ * tanh_y(N2L2E * cn);
        if (act_on) {
            cst = cn;
            wr0[(p & 1) * SLOT_H] = (_Float16)hh;
            if (u == 2 && p == T_STEPS + 1) h2f[sq][cell] = hh;  // final h2
        }
        __syncthreads();
    }

    // ---- fused projection: out[seq,:] = h2_last @ Wout^T + bout ----
    if (tid < SEQS * 11) {
        const int sq2 = tid / 11, o = tid % 11;
        float acc = bout[o];
#pragma unroll
        for (int jj = 0; jj < H; ++jj)
            acc += Wout[o * H + jj] * h2f[sq2][jj];
        out[(blockIdx.x * SEQS + sq2) * 11 + o] = acc;
    }
}

extern "C" void kernel_launch(void* const* d_in, const int* in_sizes, int n_in,
                              void* d_out, int out_size, void* d_ws, size_t ws_size,
                              hipStream_t stream) {
    const float* x    = (const float*)d_in[0];
    const float* Wih0 = (const float*)d_in[1];
    const float* Whh0 = (const float*)d_in[2];
    const float* bih0 = (const float*)d_in[3];
    const float* bhh0 = (const float*)d_in[4];
    const float* Wih1 = (const float*)d_in[5];
    const float* Whh1 = (const float*)d_in[6];
    const float* bih1 = (const float*)d_in[7];
    const float* bhh1 = (const float*)d_in[8];
    const float* Wih2 = (const float*)d_in[9];
    const float* Whh2 = (const float*)d_in[10];
    const float* bih2 = (const float*)d_in[11];
    const float* bhh2 = (const float*)d_in[12];
    const float* Wout = (const float*)d_in[13];
    const float* bout = (const float*)d_in[14];
    float* out = (float*)d_out;

    lstm3_r23<<<64, 1024, 0, stream>>>(x,
        Wih0, Whh0, bih0, bhh0,
        Wih1, Whh1, bih1, bhh1,
        Wih2, Whh2, bih2, bhh2,
        Wout, bout, out);
}

// Round 11
// 2125.772 us; speedup vs baseline: 1.1603x; 1.1603x over previous
//
#include <hip/hip_runtime.h>

#define H 64
#define T_STEPS 2048

typedef _Float16 f16x8 __attribute__((ext_vector_type(8)));
typedef float    f32x4 __attribute__((ext_vector_type(4)));

// ---- native transcendentals (R20-proven): v_exp_f32 / v_rcp_f32 ----
__device__ __forceinline__ float fexp2(float x) {
#if __has_builtin(__builtin_amdgcn_exp2f)
    return __builtin_amdgcn_exp2f(x);
#else
    float r; asm("v_exp_f32 %0, %1" : "=v"(r) : "v"(x)); return r;
#endif
}
__device__ __forceinline__ float frcp(float x) {
#if __has_builtin(__builtin_amdgcn_rcpf)
    return __builtin_amdgcn_rcpf(x);
#else
    float r; asm("v_rcp_f32 %0, %1" : "=v"(r) : "v"(x)); return r;
#endif
}
// pre-acts arrive PRE-SCALED by -log2e (i,f,o rows) / -2log2e (g rows)
__device__ __forceinline__ float sig_y(float y)  { return frcp(1.0f + fexp2(y)); }
__device__ __forceinline__ float tanh_y(float y) { return 2.0f * frcp(1.0f + fexp2(y)) - 1.0f; }
#define NL2E  (-1.44269504088896341f)
#define N2L2E (-2.88539008177792681f)

// load 8 consecutive f32, scale, -> f16x8 (setup only)
__device__ __forceinline__ f16x8 ldcvt8s(const float* __restrict__ p, float s) {
    float4 a = ((const float4*)p)[0];
    float4 c = ((const float4*)p)[1];
    f16x8 r;
    r[0]=(_Float16)(s*a.x); r[1]=(_Float16)(s*a.y);
    r[2]=(_Float16)(s*a.z); r[3]=(_Float16)(s*a.w);
    r[4]=(_Float16)(s*c.x); r[5]=(_Float16)(s*c.y);
    r[6]=(_Float16)(s*c.z); r[7]=(_Float16)(s*c.w);
    return r;
}

#define MFMA(a, b, c) __builtin_amdgcn_mfma_f32_16x16x32_f16((a), (b), (c), 0, 0, 0)

// R24: R16's WAVE-SPECIALIZED STRUCTURE + NATIVE TRANS + C-FOLDED BIAS/X.
// Cost law found via R16/R21/R23 ledgers: trans issue is PER WAVE-INSTR
// (~32 cyc/wave64), not per active lane. R23 (act on all 16 waves) =
// 160 trans instrs/block-step -> 1280 cyc/SIMD. R16 (act on 3 waves,
// SEQS=1) = 30 instrs -> <=320 cyc on any SIMD — why R16 (1855us) beats
// every later variant. R24 keeps R16's structure and removes its known
// remaining fat: (a) libm __expf/div in the act phase -> native
// v_exp/v_rcp with -log2e pre-scaled weights (R20-validated, ~3x);
// (b) bias + x-term folded into MFMA C-operand (R18/R23) so act waves
// get finished pre-activations; (c) split accumulators (R17).
// Structure: grid 256 (1 seq/block), 16 waves; all waves do the MFMA
// phase (10 MFMAs each, A in AGPRs); D-lanes (lj==0) drop pre-acts to
// gbuf; barrier; act waves 0-2 (layer w, lane = cell) do 1 update/lane;
// barrier. Pipeline L0 t=p / L1 t=p-1 / L2 t=p-2; read slot (p+1)&1,
// write slot p&1.
__global__ __launch_bounds__(1024, 4)
void lstm3_r24(const float* __restrict__ x,
               const float* __restrict__ Wih0, const float* __restrict__ Whh0,
               const float* __restrict__ bih0, const float* __restrict__ bhh0,
               const float* __restrict__ Wih1, const float* __restrict__ Whh1,
               const float* __restrict__ bih1, const float* __restrict__ bhh1,
               const float* __restrict__ Wih2, const float* __restrict__ Whh2,
               const float* __restrict__ bih2, const float* __restrict__ bhh2,
               const float* __restrict__ Wout, const float* __restrict__ bout,
               float* __restrict__ out)
{
    __shared__ __align__(16) float xs[T_STEPS * 2];   // 16 KB input seq (f32)
    // S: 2 slots x 384 halves. Rows 0-63 h0, 64-127 h1, 128-191 h2;
    // rows 192-383 permanent zeros (inactive-lane B reads).
    __shared__ __align__(16) _Float16 S[2][384];
    __shared__ __align__(16) float gbuf[3][H][4];     // scaled pre-acts
    __shared__ __align__(16) float h2f[H];

    const int tid = threadIdx.x;
    const int b   = blockIdx.x;
    const int w   = tid >> 6;          // wave 0..15 = M-tile index
    const int l   = tid & 63;
    const int lj  = l & 15;            // A row-in-tile / D col
    const int kg  = l >> 4;            // k-group / D row-quad
    const int cell = 4 * w + kg;       // cell of this lane's D rows

    // ---- stage x[b,:,:]: one float4 per thread ----
    ((float4*)xs)[tid] = ((const float4*)(x + (size_t)b * T_STEPS * 2))[tid];

    // ---- A-fragments (R16-proven mapping), pre-scaled by gate row ----
    const int cellA = 4 * w + (lj >> 2);
    const int gateA = lj & 3;
    const int wrow  = gateA * H + cellA;
    const int kc    = kg * 8;
    const float sA  = (gateA == 2) ? N2L2E : NL2E;

    f16x8 A00 = ldcvt8s(Whh0 + wrow * H + kc,      sA);   // L0 <- h0 lo
    f16x8 A01 = ldcvt8s(Whh0 + wrow * H + 32 + kc, sA);   // L0 <- h0 hi
    f16x8 A10 = ldcvt8s(Wih1 + wrow * H + kc,      sA);   // L1 <- h0 lo
    f16x8 A11 = ldcvt8s(Wih1 + wrow * H + 32 + kc, sA);   // L1 <- h0 hi
    f16x8 A12 = ldcvt8s(Whh1 + wrow * H + kc,      sA);   // L1 <- h1 lo
    f16x8 A13 = ldcvt8s(Whh1 + wrow * H + 32 + kc, sA);   // L1 <- h1 hi
    f16x8 A20 = ldcvt8s(Wih2 + wrow * H + kc,      sA);   // L2 <- h1 lo
    f16x8 A21 = ldcvt8s(Wih2 + wrow * H + 32 + kc, sA);   // L2 <- h1 hi
    f16x8 A22 = ldcvt8s(Whh2 + wrow * H + kc,      sA);   // L2 <- h2 lo
    f16x8 A23 = ldcvt8s(Whh2 + wrow * H + 32 + kc, sA);   // L2 <- h2 hi
    asm volatile("" : "+a"(A00), "+a"(A01), "+a"(A10), "+a"(A11));
    asm volatile("" : "+a"(A12), "+a"(A13), "+a"(A20), "+a"(A21));
    asm volatile("" : "+a"(A22), "+a"(A23));

    // ---- C-operand bias frags (rows = gates of `cell`), pre-scaled ----
    f32x4 cb0, cb1, cb2;
    float wx[8];
#pragma unroll
    for (int r = 0; r < 4; ++r) {
        const float sr = (r == 2) ? N2L2E : NL2E;
        cb0[r] = sr * (bih0[r * H + cell] + bhh0[r * H + cell]);
        cb1[r] = sr * (bih1[r * H + cell] + bhh1[r * H + cell]);
        cb2[r] = sr * (bih2[r * H + cell] + bhh2[r * H + cell]);
        wx[2 * r]     = sr * Wih0[(r * H + cell) * 2];
        wx[2 * r + 1] = sr * Wih0[(r * H + cell) * 2 + 1];
    }
    float cst = 0.f;                   // act-wave cell state (waves 0-2)

    // ---- zero S (both slots incl. zero pad) ----
    if (tid < 384) ((float*)S)[tid] = 0.f;
    __syncthreads();

    // B-frag byte offset: active lanes (lj==0) read their k-group;
    // inactive lanes read the zero pad (broadcast). (R16-proven.)
    const char* Sb  = (const char*)S;
    const int  bofs = (lj == 0) ? (kg * 16) : 384;
    const f32x4 z = {0.f, 0.f, 0.f, 0.f};

#pragma unroll 1
    for (int p = 0; p <= T_STEPS + 1; ++p) {
        const bool on0 = (p < T_STEPS);
        const bool on1 = (p >= 1) && (p <= T_STEPS);
        const bool on2 = (p >= 2);

        const int so = ((p + 1) & 1) * 768;        // read-slot byte offset
        const char* Bp = Sb + (bofs + so);
        f16x8 b0 = *(const f16x8*)(Bp + 0);        // h0 lo
        f16x8 b1 = *(const f16x8*)(Bp + 64);       // h0 hi
        f16x8 b2 = *(const f16x8*)(Bp + 128);      // h1 lo
        f16x8 b3 = *(const f16x8*)(Bp + 192);      // h1 hi
        f16x8 b4 = *(const f16x8*)(Bp + 256);      // h2 lo
        f16x8 b5 = *(const f16x8*)(Bp + 320);      // h2 hi

        // L0 C-operand: scaled bias + scaled x-term (uniform x broadcast)
        const int px = on0 ? p : (T_STEPS - 1);
        float2 xt = *(const float2*)&xs[2 * px];
        f32x4 c0;
#pragma unroll
        for (int r = 0; r < 4; ++r)
            c0[r] = cb0[r] + wx[2 * r] * xt.x + wx[2 * r + 1] * xt.y;

        // ---- 10 MFMAs (biases ride C; split accumulators) ----
        f32x4 g0 = z, g1 = z, g2 = z;
        if (on0) { g0 = MFMA(A00, b0, c0);  g0 = MFMA(A01, b1, g0); }
        if (on1) {
            f32x4 ga = MFMA(A10, b0, cb1); ga = MFMA(A11, b1, ga);
            f32x4 gb = MFMA(A12, b2, z);   gb = MFMA(A13, b3, gb);
            g1 = ga + gb;
        }
        if (on2) {
            f32x4 gc = MFMA(A20, b2, cb2); gc = MFMA(A21, b3, gc);
            f32x4 gd = MFMA(A22, b4, z);   gd = MFMA(A23, b5, gd);
            g2 = gc + gd;
        }

        // ---- D-lanes drop finished pre-acts to gbuf ----
        if (lj == 0) {
            *(f32x4*)&gbuf[0][cell][0] = g0;
            *(f32x4*)&gbuf[1][cell][0] = g1;
            *(f32x4*)&gbuf[2][cell][0] = g2;
        }
        __syncthreads();

        // ---- act waves 0-2 (layer w, lane = cell): 1 update/lane ----
        if (w < 3) {
            const bool on = (w == 0) ? on0 : (w == 1) ? on1 : on2;
            f32x4 g = *(const f32x4*)&gbuf[w][l][0];
            float i_ = sig_y(g[0]), f_ = sig_y(g[1]);
            float gg = tanh_y(g[2]), o_ = sig_y(g[3]);
            float cn = f_ * cst + i_ * gg;
            float hh = o_ * tanh_y(N2L2E * cn);
            if (on) {
                cst = cn;
                S[p & 1][w * H + l] = (_Float16)hh;
                if (w == 2 && p == T_STEPS + 1) h2f[l] = hh;   // final h2
            }
        }
        __syncthreads();
    }

    // ---- fused projection: out[b,:] = h2_last @ Wout^T + bout ----
    if (tid < 11) {
        float acc = bout[tid];
#pragma unroll
        for (int jj = 0; jj < H; ++jj)
            acc += Wout[tid * H + jj] * h2f[jj];
        out[b * 11 + tid] = acc;
    }
}

extern "C" void kernel_launch(void* const* d_in, const int* in_sizes, int n_in,
                              void* d_out, int out_size, void* d_ws, size_t ws_size,
                              hipStream_t stream) {
    const float* x    = (const float*)d_in[0];
    const float* Wih0 = (const float*)d_in[1];
    const float* Whh0 = (const float*)d_in[2];
    const float* bih0 = (const float*)d_in[3];
    const float* bhh0 = (const float*)d_in[4];
    const float* Wih1 = (const float*)d_in[5];
    const float* Whh1 = (const float*)d_in[6];
    const float* bih1 = (const float*)d_in[7];
    const float* bhh1 = (const float*)d_in[8];
    const float* Wih2 = (const float*)d_in[9];
    const float* Whh2 = (const float*)d_in[10];
    const float* bih2 = (const float*)d_in[11];
    const float* bhh2 = (const float*)d_in[12];
    const float* Wout = (const float*)d_in[13];
    const float* bout = (const float*)d_in[14];
    float* out = (float*)d_out;

    lstm3_r24<<<256, 1024, 0, stream>>>(x,
        Wih0, Whh0, bih0, bhh0,
        Wih1, Whh1, bih1, bhh1,
        Wih2, Whh2, bih2, bhh2,
        Wout, bout, out);
}

// Round 12
// 1940.652 us; speedup vs baseline: 1.2710x; 1.0954x over previous
//
#include <hip/hip_runtime.h>

#define H 64
#define T_STEPS 2048

typedef _Float16 f16x8 __attribute__((ext_vector_type(8)));
typedef float    f32x4 __attribute__((ext_vector_type(4)));

// ---- native transcendentals (R20-proven): v_exp_f32 / v_rcp_f32 ----
__device__ __forceinline__ float fexp2(float x) {
#if __has_builtin(__builtin_amdgcn_exp2f)
    return __builtin_amdgcn_exp2f(x);
#else
    float r; asm("v_exp_f32 %0, %1" : "=v"(r) : "v"(x)); return r;
#endif
}
__device__ __forceinline__ float frcp(float x) {
#if __has_builtin(__builtin_amdgcn_rcpf)
    return __builtin_amdgcn_rcpf(x);
#else
    float r; asm("v_rcp_f32 %0, %1" : "=v"(r) : "v"(x)); return r;
#endif
}
// pre-acts arrive PRE-SCALED by -log2e (i,f,o rows) / -2log2e (g rows)
__device__ __forceinline__ float sig_y(float y)  { return frcp(1.0f + fexp2(y)); }
__device__ __forceinline__ float tanh_y(float y) { return 2.0f * frcp(1.0f + fexp2(y)) - 1.0f; }
#define NL2E  (-1.44269504088896341f)
#define N2L2E (-2.88539008177792681f)

// load 8 consecutive f32, scale, -> f16x8 (setup only)
__device__ __forceinline__ f16x8 ldcvt8s(const float* __restrict__ p, float s) {
    float4 a = ((const float4*)p)[0];
    float4 c = ((const float4*)p)[1];
    f16x8 r;
    r[0]=(_Float16)(s*a.x); r[1]=(_Float16)(s*a.y);
    r[2]=(_Float16)(s*a.z); r[3]=(_Float16)(s*a.w);
    r[4]=(_Float16)(s*c.x); r[5]=(_Float16)(s*c.y);
    r[6]=(_Float16)(s*c.z); r[7]=(_Float16)(s*c.w);
    return r;
}

#define MFMA(a, b, c) __builtin_amdgcn_mfma_f32_16x16x32_f16((a), (b), (c), 0, 0, 0)

// R25: CONTROLLED A/B — R16's EXACT STRUCTURE + NATIVE TRANS ONLY.
// R24 post-mortem: C-folding bias/x into per-iteration VGPR C-operands
// regressed (+570 VALU-cyc/SIMD/step, ~70 instrs/wave churn) — fresh
// VGPR C-inputs each step force register churn against AGPR-parked A.
// R25 reverts to R16's z-chained MFMAs and act-phase bias/x adds, and
// keeps ONLY the load-time change: gate rows of A pre-scaled by -log2e
// (-2log2e for g) so the act phase uses native sig_y/tanh_y
// (exp2+add+rcp; no IEEE div, no libm). Act waves add SCALED bias/x.
// Structure (R16-proven, 1855us): grid 256 (1 seq/block), 16 waves; all
// waves MFMA phase (10 z-chained MFMAs, A in AGPRs); D-lanes (lj==0)
// drop pre-acts to gbuf; barrier; act waves 0-2 (layer w, lane=cell),
// 1 update/lane; barrier. L0 t=p / L1 t=p-1 / L2 t=p-2; read slot
// (p+1)&1, write slot p&1.
__global__ __launch_bounds__(1024, 4)
void lstm3_r25(const float* __restrict__ x,
               const float* __restrict__ Wih0, const float* __restrict__ Whh0,
               const float* __restrict__ bih0, const float* __restrict__ bhh0,
               const float* __restrict__ Wih1, const float* __restrict__ Whh1,
               const float* __restrict__ bih1, const float* __restrict__ bhh1,
               const float* __restrict__ Wih2, const float* __restrict__ Whh2,
               const float* __restrict__ bih2, const float* __restrict__ bhh2,
               const float* __restrict__ Wout, const float* __restrict__ bout,
               float* __restrict__ out)
{
    __shared__ __align__(16) float xs[T_STEPS * 2];   // 16 KB input seq (f32)
    // S: 2 slots x 384 halves. Rows 0-63 h0, 64-127 h1, 128-191 h2;
    // rows 192-383 permanent zeros (inactive-lane B reads).
    __shared__ __align__(16) _Float16 S[2][384];
    __shared__ __align__(16) float gbuf[3][H][4];     // scaled pre-acts (no bias)
    __shared__ __align__(16) float h2f[H];

    const int tid = threadIdx.x;
    const int b   = blockIdx.x;
    const int w   = tid >> 6;          // wave 0..15 = M-tile index
    const int l   = tid & 63;
    const int lj  = l & 15;            // A row-in-tile / D col
    const int kg  = l >> 4;            // k-group / D row-quad
    const int cell = 4 * w + kg;       // cell of this lane's D rows

    // ---- stage x[b,:,:]: one float4 per thread ----
    ((float4*)xs)[tid] = ((const float4*)(x + (size_t)b * T_STEPS * 2))[tid];

    // ---- A-fragments (R16-proven mapping), pre-scaled by gate row ----
    const int cellA = 4 * w + (lj >> 2);
    const int gateA = lj & 3;
    const int wrow  = gateA * H + cellA;
    const int kc    = kg * 8;
    const float sA  = (gateA == 2) ? N2L2E : NL2E;

    f16x8 A00 = ldcvt8s(Whh0 + wrow * H + kc,      sA);   // L0 <- h0 lo
    f16x8 A01 = ldcvt8s(Whh0 + wrow * H + 32 + kc, sA);   // L0 <- h0 hi
    f16x8 A10 = ldcvt8s(Wih1 + wrow * H + kc,      sA);   // L1 <- h0 lo
    f16x8 A11 = ldcvt8s(Wih1 + wrow * H + 32 + kc, sA);   // L1 <- h0 hi
    f16x8 A12 = ldcvt8s(Whh1 + wrow * H + kc,      sA);   // L1 <- h1 lo
    f16x8 A13 = ldcvt8s(Whh1 + wrow * H + 32 + kc, sA);   // L1 <- h1 hi
    f16x8 A20 = ldcvt8s(Wih2 + wrow * H + kc,      sA);   // L2 <- h1 lo
    f16x8 A21 = ldcvt8s(Wih2 + wrow * H + 32 + kc, sA);   // L2 <- h1 hi
    f16x8 A22 = ldcvt8s(Whh2 + wrow * H + kc,      sA);   // L2 <- h2 lo
    f16x8 A23 = ldcvt8s(Whh2 + wrow * H + 32 + kc, sA);   // L2 <- h2 hi
    // park in AGPRs once; MFMA consumes them there (no per-step copies)
    asm volatile("" : "+a"(A00), "+a"(A01), "+a"(A10), "+a"(A11));
    asm volatile("" : "+a"(A12), "+a"(A13), "+a"(A20), "+a"(A21));
    asm volatile("" : "+a"(A22), "+a"(A23));

    // ---- act-wave constants (waves 0-2; lane = cell), pre-scaled ----
    float biasv[4], wxv[8];
    float cst = 0.f;
    if (w < 3) {
        const float* bi = (w == 0) ? bih0 : (w == 1) ? bih1 : bih2;
        const float* bh = (w == 0) ? bhh0 : (w == 1) ? bhh1 : bhh2;
#pragma unroll
        for (int g = 0; g < 4; ++g) {
            const float sr = (g == 2) ? N2L2E : NL2E;
            biasv[g] = sr * (bi[g * H + l] + bh[g * H + l]);
            if (w == 0) {
                wxv[2 * g]     = sr * Wih0[(g * H + l) * 2];
                wxv[2 * g + 1] = sr * Wih0[(g * H + l) * 2 + 1];
            }
        }
    }

    // ---- zero S (both slots incl. zero pad) ----
    if (tid < 384) ((float*)S)[tid] = 0.f;
    __syncthreads();

    // B-frag byte offset: active lanes (lj==0) read their k-group;
    // inactive lanes read the zero pad (broadcast). (R16-proven.)
    const char* Sb  = (const char*)S;
    const int  bofs = (lj == 0) ? (kg * 16) : 384;
    const f32x4 z = {0.f, 0.f, 0.f, 0.f};

#pragma unroll 1
    for (int p = 0; p <= T_STEPS + 1; ++p) {
        const bool on0 = (p < T_STEPS);
        const bool on1 = (p >= 1) && (p <= T_STEPS);
        const bool on2 = (p >= 2);

        const int so = ((p + 1) & 1) * 768;        // read-slot byte offset
        const char* Bp = Sb + (bofs + so);
        f16x8 b0 = *(const f16x8*)(Bp + 0);        // h0 lo
        f16x8 b1 = *(const f16x8*)(Bp + 64);       // h0 hi
        f16x8 b2 = *(const f16x8*)(Bp + 128);      // h1 lo
        f16x8 b3 = *(const f16x8*)(Bp + 192);      // h1 hi
        f16x8 b4 = *(const f16x8*)(Bp + 256);      // h2 lo
        f16x8 b5 = *(const f16x8*)(Bp + 320);      // h2 hi

        // ---- 10 z-chained MFMAs (R16 pattern; split accumulators) ----
        f32x4 g0 = z, g1 = z, g2 = z;
        if (on0) { g0 = MFMA(A00, b0, z);  g0 = MFMA(A01, b1, g0); }
        if (on1) {
            f32x4 ga = MFMA(A10, b0, z);  ga = MFMA(A11, b1, ga);
            f32x4 gb = MFMA(A12, b2, z);  gb = MFMA(A13, b3, gb);
            g1 = ga + gb;
        }
        if (on2) {
            f32x4 gc = MFMA(A20, b2, z);  gc = MFMA(A21, b3, gc);
            f32x4 gd = MFMA(A22, b4, z);  gd = MFMA(A23, b5, gd);
            g2 = gc + gd;
        }

        // ---- D-lanes drop pre-acts (no bias yet) to gbuf ----
        if (lj == 0) {
            *(f32x4*)&gbuf[0][cell][0] = g0;
            *(f32x4*)&gbuf[1][cell][0] = g1;
            *(f32x4*)&gbuf[2][cell][0] = g2;
        }
        __syncthreads();

        // ---- act waves 0-2 (layer w, lane = cell): 1 update/lane ----
        if (w < 3) {
            const bool on = (w == 0) ? on0 : (w == 1) ? on1 : on2;
            f32x4 g = *(const f32x4*)&gbuf[w][l][0];
            float pi = g[0] + biasv[0], pf = g[1] + biasv[1];
            float pg = g[2] + biasv[2], po = g[3] + biasv[3];
            if (w == 0) {              // scaled x-term (wave 0 only)
                const int px = on0 ? p : 0;
                float2 xt = *(const float2*)&xs[2 * px];
                pi += wxv[0] * xt.x + wxv[1] * xt.y;
                pf += wxv[2] * xt.x + wxv[3] * xt.y;
                pg += wxv[4] * xt.x + wxv[5] * xt.y;
                po += wxv[6] * xt.x + wxv[7] * xt.y;
            }
            float i_ = sig_y(pi), f_ = sig_y(pf);
            float gg = tanh_y(pg), o_ = sig_y(po);
            float cn = f_ * cst + i_ * gg;
            float hh = o_ * tanh_y(N2L2E * cn);
            if (on) {
                cst = cn;
                S[p & 1][w * H + l] = (_Float16)hh;
                if (w == 2 && p == T_STEPS + 1) h2f[l] = hh;   // final h2
            }
        }
        __syncthreads();
    }

    // ---- fused projection: out[b,:] = h2_last @ Wout^T + bout ----
    if (tid < 11) {
        float acc = bout[tid];
#pragma unroll
        for (int jj = 0; jj < H; ++jj)
            acc += Wout[tid * H + jj] * h2f[jj];
        out[b * 11 + tid] = acc;
    }
}

extern "C" void kernel_launch(void* const* d_in, const int* in_sizes, int n_in,
                              void* d_out, int out_size, void* d_ws, size_t ws_size,
                              hipStream_t stream) {
    const float* x    = (const float*)d_in[0];
    const float* Wih0 = (const float*)d_in[1];
    const float* Whh0 = (const float*)d_in[2];
    const float* bih0 = (const float*)d_in[3];
    const float* bhh0 = (const float*)d_in[4];
    const float* Wih1 = (const float*)d_in[5];
    const float* Whh1 = (const float*)d_in[6];
    const float* bih1 = (const float*)d_in[7];
    const float* bhh1 = (const float*)d_in[8];
    const float* Wih2 = (const float*)d_in[9];
    const float* Whh2 = (const float*)d_in[10];
    const float* bih2 = (const float*)d_in[11];
    const float* bhh2 = (const float*)d_in[12];
    const float* Wout = (const float*)d_in[13];
    const float* bout = (const float*)d_in[14];
    float* out = (float*)d_out;

    lstm3_r25<<<256, 1024, 0, stream>>>(x,
        Wih0, Whh0, bih0, bhh0,
        Wih1, Whh1, bih1, bhh1,
        Wih2, Whh2, bih2, bhh2,
        Wout, bout, out);
}